// Round 5
// baseline (155.486 us; speedup 1.0000x reference)
//
#include <hip/hip_runtime.h>
#include <hip/hip_bf16.h>

// Shapes fixed by the reference's setup_inputs
#define BS    64        // B*S = 4*16
#define DDIM  512       // attention dim (K)
#define NV    32000     // vocab
#define TD    18        // tree depth
#define INNER 31999     // V-1 internal nodes (N)
#define ROWX  32000     // x-table row stride in u16 elems (64,000 B)

#define CFG_IDX_I64   8u

typedef __attribute__((ext_vector_type(8))) short short8;
typedef __attribute__((ext_vector_type(4))) float floatx4;

__device__ __forceinline__ float bf16_to_f32(unsigned short u) {
    union { unsigned int i; float f; } v; v.i = ((unsigned int)u) << 16; return v.f;
}
__device__ __forceinline__ unsigned short f32_to_bf16(float f) {
    union { float f; unsigned int i; } v; v.f = f;
    unsigned int r = v.i + 0x7FFFu + ((v.i >> 16) & 1u);   // RNE
    return (unsigned short)(r >> 16);
}

// --------------------------------------------------------------------------
// Tiny probe: int64 vs int32 path_index (contract says int32; this is free
// insurance). int64 => hi (odd) u32 words all zero over 8 probes.
// --------------------------------------------------------------------------
__global__ void probe_idx(const unsigned int* __restrict__ idx_w,
                          unsigned int* __restrict__ cfg)
{
    if (threadIdx.x == 0) {
        bool i64 = true;
        for (int i = 1; i < 16; i += 2) i64 &= (idx_w[i] == 0u);
        *cfg = i64 ? CFG_IDX_I64 : 0u;
    }
}

// --------------------------------------------------------------------------
// att fp32 -> bf16.  32 x 256 threads, one float4 each (8192 = 32768 elems).
// --------------------------------------------------------------------------
__global__ __launch_bounds__(256) void cvt_att(
    const float4* __restrict__ att, ushort4* __restrict__ attb)
{
    int i = blockIdx.x * 256 + threadIdx.x;          // 0..8191
    float4 a = att[i];
    ushort4 r;
    r.x = f32_to_bf16(a.x); r.y = f32_to_bf16(a.y);
    r.z = f32_to_bf16(a.z); r.w = f32_to_bf16(a.w);
    attb[i] = r;
}

// --------------------------------------------------------------------------
// idx2[j] = 2*path_index[j] + (path_sign[j] < 0), u16.  2250 x 256 = 576000.
// --------------------------------------------------------------------------
__global__ __launch_bounds__(256) void prep_idx2(
    const int* __restrict__ idx,                 // int32 view (covers i64 lo-words)
    const unsigned int* __restrict__ signbits,   // fp32 path_sign raw bits
    unsigned short* __restrict__ idx2,
    const unsigned int* __restrict__ cfgp)
{
    const unsigned int cfg = *cfgp;
    int i = blockIdx.x * 256 + threadIdx.x;
    int v = (cfg & CFG_IDX_I64) ? idx[2 * i] : idx[i];
    idx2[i] = (unsigned short)((v << 1) | (int)(signbits[i] >> 31));
}

// --------------------------------------------------------------------------
// x[m][n] = att[m,:]·weight[n,:]  (bf16 MFMA 16x16x32; fp32 weight converted
// inline — each element used exactly once, traffic-optimal). Store x bf16.
// Grid 500 x 256 (4 waves; wave = 16 n-cols x full M=64 via 4 m-tiles).
// C/D map (verified m89): col = lane&15, row = (lane>>4)*4 + reg.
// --------------------------------------------------------------------------
__global__ __launch_bounds__(256) void gemm_x(
    const unsigned short* __restrict__ attb,     // [64][512] bf16
    const float* __restrict__ weight,            // [INNER][512] fp32
    unsigned short* __restrict__ tabx)           // [64][ROWX] bf16
{
    const int lane = threadIdx.x & 63;
    const int wave = threadIdx.x >> 6;
    const int nb   = blockIdx.x * 64 + wave * 16;
    const int l15  = lane & 15;
    const int quad = lane >> 4;

    floatx4 acc[4];
#pragma unroll
    for (int i = 0; i < 4; ++i) acc[i] = (floatx4){0.f, 0.f, 0.f, 0.f};

    int brow = nb + l15;
    if (brow > INNER - 1) brow = INNER - 1;          // clamp; stores guarded
    const float*          bbase = weight + (size_t)brow * DDIM + quad * 8;
    const unsigned short* abase = attb + l15 * DDIM + quad * 8;

#pragma unroll 4
    for (int k0 = 0; k0 < DDIM; k0 += 32) {
        float4 b0 = *(const float4*)(bbase + k0);
        float4 b1 = *(const float4*)(bbase + k0 + 4);
        short8 bfrag;
        bfrag[0] = (short)f32_to_bf16(b0.x); bfrag[1] = (short)f32_to_bf16(b0.y);
        bfrag[2] = (short)f32_to_bf16(b0.z); bfrag[3] = (short)f32_to_bf16(b0.w);
        bfrag[4] = (short)f32_to_bf16(b1.x); bfrag[5] = (short)f32_to_bf16(b1.y);
        bfrag[6] = (short)f32_to_bf16(b1.z); bfrag[7] = (short)f32_to_bf16(b1.w);
#pragma unroll
        for (int mt = 0; mt < 4; ++mt) {
            short8 afrag = *(const short8*)(abase + mt * 16 * DDIM + k0);
            acc[mt] = __builtin_amdgcn_mfma_f32_16x16x32_bf16(afrag, bfrag, acc[mt], 0, 0, 0);
        }
    }

    const int n = nb + l15;
    if (n < INNER) {
#pragma unroll
        for (int mt = 0; mt < 4; ++mt) {
#pragma unroll
            for (int r = 0; r < 4; ++r) {
                const int m = mt * 16 + quad * 4 + r;
                tabx[m * ROWX + n] = f32_to_bf16(acc[mt][r]);
            }
        }
    }
}

// --------------------------------------------------------------------------
// out[bs][v] = sum_t [ -softplus(-x) - bit*x ],  x = tabx[bs][idx2[v*18+t]>>1]
//   bit=0: log sigmoid(x);  bit=1: log(1-sigmoid(x)) = log sigmoid(x) - x.
// Stage full 64,000 B x-row in static LDS.  Grid (4 chunks, 64 bs) x 1024.
// OUTPUT IS FP32 (reference returns float32; harness contract "else float*").
// --------------------------------------------------------------------------
__global__ __launch_bounds__(1024) void gather_logsig(
    const unsigned short* __restrict__ tabx,     // [64][ROWX] bf16
    const unsigned short* __restrict__ idx2,     // [NV*TD] u16 (2n+bit)
    float* __restrict__ out)                     // [64][NV] fp32
{
    __shared__ __align__(16) unsigned short lds[ROWX];   // 64,000 B
    const int bs    = blockIdx.y;
    const int vbase = blockIdx.x * 8000;
    const int tid   = threadIdx.x;

    const uint4* src = (const uint4*)(tabx + bs * ROWX);
    for (int i = tid; i < ROWX / 8; i += 1024) ((uint4*)lds)[i] = src[i];
    __syncthreads();

#pragma unroll
    for (int s = 0; s < 8; ++s) {
        int r = s * 1024 + tid;
        if (r < 8000) {
            const unsigned short* ip = idx2 + (size_t)(vbase + r) * TD;
            float sum = 0.f;
#pragma unroll
            for (int t = 0; t < TD; ++t) {
                unsigned int e = ip[t];
                float x = bf16_to_f32(lds[e >> 1]);
                float sp = fmaxf(-x, 0.f) + __logf(1.f + __expf(-fabsf(x)));  // softplus(-x)
                sum -= sp + ((e & 1u) ? x : 0.f);
            }
            out[bs * NV + vbase + r] = sum;     // fp32 store
        }
    }
}

extern "C" void kernel_launch(void* const* d_in, const int* in_sizes, int n_in,
                              void* d_out, int out_size, void* d_ws, size_t ws_size,
                              hipStream_t stream)
{
    const float*        att    = (const float*)d_in[0];        // fp32 [4,16,512]
    const float*        weight = (const float*)d_in[1];        // fp32 [31999,512]
    const int*          pidx   = (const int*)d_in[2];          // int32 (probe: i64) [576000]
    const unsigned int* psign  = (const unsigned int*)d_in[3]; // fp32 bits [576000]
    // d_in[4] path_bias (redundant: bias=(1-sign)/2), d_in[5..6] scalars
    float* out = (float*)d_out;                                // fp32 [64][32000]

    // workspace: 5,313,600 B total (16B-aligned offsets)
    char* ws = (char*)d_ws;
    unsigned short* tabx = (unsigned short*)ws;                // 4,096,000 B
    unsigned short* idx2 = (unsigned short*)(ws + 4096000);    // 1,152,000 B
    ushort4*        attb = (ushort4*)       (ws + 5248000);    //    65,536 B
    unsigned int*   cfg  = (unsigned int*)  (ws + 5313536);    //        64 B

    probe_idx<<<1, 64, 0, stream>>>((const unsigned int*)pidx, cfg);
    cvt_att  <<<32,   256, 0, stream>>>((const float4*)att, attb);
    prep_idx2<<<2250, 256, 0, stream>>>(pidx, psign, idx2, cfg);
    gemm_x   <<<500,  256, 0, stream>>>((const unsigned short*)attb, weight, tabx);
    gather_logsig<<<dim3(4, BS), 1024, 0, stream>>>(tabx, idx2, out);
}

// Round 6
// 145.036 us; speedup vs baseline: 1.0721x; 1.0721x over previous
//
#include <hip/hip_runtime.h>
#include <hip/hip_bf16.h>

// Shapes fixed by the reference's setup_inputs
#define BS    64        // B*S = 4*16
#define DDIM  512       // attention dim (K)
#define NV    32000     // vocab
#define TD    18        // tree depth
#define INNER 31999     // V-1 internal nodes (N)
#define ROWP  32000     // pair-table row stride in u32 (= 128,000 B / bs-row)

typedef __attribute__((ext_vector_type(8))) short short8;
typedef __attribute__((ext_vector_type(4))) float floatx4;

__device__ __forceinline__ float bf16_to_f32(unsigned short u) {
    union { unsigned int i; float f; } v; v.i = ((unsigned int)u) << 16; return v.f;
}
__device__ __forceinline__ unsigned short f32_to_bf16(float f) {
    union { float f; unsigned int i; } v; v.f = f;
    unsigned int r = v.i + 0x7FFFu + ((v.i >> 16) & 1u);   // RNE
    return (unsigned short)(r >> 16);
}

// --------------------------------------------------------------------------
// Fused prep. Blocks [0,2250): idx2T[t][v] = 2*idx[v*18+t] + (sign<0), u16,
// TRANSPOSED so the gather's per-t index loads are lane-coalesced.
// Blocks [2250,2282): att fp32 -> bf16 (8192 float4).
// int64-vs-int32 idx probe inlined (first 64 B, uniform, always in-bounds).
// --------------------------------------------------------------------------
#define IDXB 2250
__global__ __launch_bounds__(256) void prep(
    const int* __restrict__ idx,
    const unsigned int* __restrict__ signbits,   // fp32 path_sign raw bits
    unsigned short* __restrict__ idx2T,          // [TD][NV] u16
    const float4* __restrict__ att,
    ushort4* __restrict__ attb)
{
    const int b = blockIdx.x;
    if (b < IDXB) {
        // i64 iff first 8 odd u32 words are all zero (P_err ~ (1/32000)^8)
        const unsigned int* w = (const unsigned int*)idx;
        bool i64 = true;
#pragma unroll
        for (int j = 1; j < 16; j += 2) i64 &= (w[j] == 0u);
        int o = b * 256 + threadIdx.x;           // transposed position t*NV+v
        int t = o / NV, v = o - t * NV;
        int i = v * TD + t;                      // source position
        int val = i64 ? idx[2 * i] : idx[i];
        idx2T[o] = (unsigned short)((val << 1) | (int)(signbits[i] >> 31));
    } else {
        int i = (b - IDXB) * 256 + threadIdx.x;  // 0..8191
        float4 a = att[i];
        ushort4 r;
        r.x = f32_to_bf16(a.x); r.y = f32_to_bf16(a.y);
        r.z = f32_to_bf16(a.z); r.w = f32_to_bf16(a.w);
        attb[i] = r;
    }
}

// --------------------------------------------------------------------------
// x[m][n] = att[m,:]·weight[n,:] (bf16 MFMA 16x16x32; fp32 weight converted
// inline). Epilogue: lp = log sigmoid(x) = -softplus(-x); lm = lp - x.
// Pack both bf16 into one u32: pairs[m][n] = (lm<<16)|lp.  Softplus runs
// HERE (2.05M evals) instead of in the gather (36.9M evals) — 18x fewer.
// Grid 500 x 256 (4 waves; wave = 16 n-cols x full M=64 via 4 m-tiles).
// C/D map (m89): col = lane&15, row = (lane>>4)*4 + reg.
// --------------------------------------------------------------------------
__global__ __launch_bounds__(256) void gemm_logsig(
    const unsigned short* __restrict__ attb,     // [64][512] bf16
    const float* __restrict__ weight,            // [INNER][512] fp32
    unsigned int* __restrict__ pairs)            // [64][ROWP] u32 (lm,lp)
{
    const int lane = threadIdx.x & 63;
    const int wave = threadIdx.x >> 6;
    const int nb   = blockIdx.x * 64 + wave * 16;
    const int l15  = lane & 15;
    const int quad = lane >> 4;

    floatx4 acc[4];
#pragma unroll
    for (int i = 0; i < 4; ++i) acc[i] = (floatx4){0.f, 0.f, 0.f, 0.f};

    int brow = nb + l15;
    if (brow > INNER - 1) brow = INNER - 1;          // clamp; stores guarded
    const float*          bbase = weight + (size_t)brow * DDIM + quad * 8;
    const unsigned short* abase = attb + l15 * DDIM + quad * 8;

#pragma unroll 4
    for (int k0 = 0; k0 < DDIM; k0 += 32) {
        float4 b0 = *(const float4*)(bbase + k0);
        float4 b1 = *(const float4*)(bbase + k0 + 4);
        short8 bfrag;
        bfrag[0] = (short)f32_to_bf16(b0.x); bfrag[1] = (short)f32_to_bf16(b0.y);
        bfrag[2] = (short)f32_to_bf16(b0.z); bfrag[3] = (short)f32_to_bf16(b0.w);
        bfrag[4] = (short)f32_to_bf16(b1.x); bfrag[5] = (short)f32_to_bf16(b1.y);
        bfrag[6] = (short)f32_to_bf16(b1.z); bfrag[7] = (short)f32_to_bf16(b1.w);
#pragma unroll
        for (int mt = 0; mt < 4; ++mt) {
            short8 afrag = *(const short8*)(abase + mt * 16 * DDIM + k0);
            acc[mt] = __builtin_amdgcn_mfma_f32_16x16x32_bf16(afrag, bfrag, acc[mt], 0, 0, 0);
        }
    }

    const int n = nb + l15;
    if (n < INNER) {
#pragma unroll
        for (int mt = 0; mt < 4; ++mt) {
#pragma unroll
            for (int r = 0; r < 4; ++r) {
                const int m = mt * 16 + quad * 4 + r;
                float x = acc[mt][r];
                float lp = -(fmaxf(-x, 0.f) + __logf(1.f + __expf(-fabsf(x))));
                float lm = lp - x;
                pairs[m * ROWP + n] = (unsigned int)f32_to_bf16(lp)
                                    | ((unsigned int)f32_to_bf16(lm) << 16);
            }
        }
    }
}

// --------------------------------------------------------------------------
// out[bs][v] = sum_t half(pairs[bs][e>>1], e&1),  e = idx2T[t][v].
// Stage the full 128,000 B pair row in dynamic LDS (proven safe in R1).
// Gather body is ds_read_b32 + half-select + add — no transcendentals.
// Grid (4 chunks, 64 bs) x 1024 threads.
// --------------------------------------------------------------------------
__global__ __launch_bounds__(1024) void gather_pairs(
    const unsigned int* __restrict__ pairs,      // [64][ROWP] u32
    const unsigned short* __restrict__ idx2T,    // [TD][NV] u16
    float* __restrict__ out)                     // [64][NV] fp32
{
    extern __shared__ unsigned int lds32[];      // ROWP u32 = 128,000 B
    const int bs    = blockIdx.y;
    const int vbase = blockIdx.x * 8000;
    const int tid   = threadIdx.x;

    const uint4* src = (const uint4*)(pairs + (size_t)bs * ROWP);
    for (int i = tid; i < ROWP / 4; i += 1024) ((uint4*)lds32)[i] = src[i];
    __syncthreads();

#pragma unroll
    for (int s = 0; s < 8; ++s) {
        int r = s * 1024 + tid;
        if (r < 8000) {
            const unsigned short* col = idx2T + vbase + r;   // stride NV per t
            float sum = 0.f;
#pragma unroll
            for (int t = 0; t < TD; ++t) {
                unsigned int e = col[(size_t)t * NV];
                unsigned int p = lds32[e >> 1];
                unsigned short h = (e & 1u) ? (unsigned short)(p >> 16)
                                            : (unsigned short)(p & 0xFFFFu);
                sum += bf16_to_f32(h);
            }
            out[bs * NV + vbase + r] = sum;
        }
    }
}

extern "C" void kernel_launch(void* const* d_in, const int* in_sizes, int n_in,
                              void* d_out, int out_size, void* d_ws, size_t ws_size,
                              hipStream_t stream)
{
    const float*        att    = (const float*)d_in[0];        // fp32 [4,16,512]
    const float*        weight = (const float*)d_in[1];        // fp32 [31999,512]
    const int*          pidx   = (const int*)d_in[2];          // int32/int64 [576000]
    const unsigned int* psign  = (const unsigned int*)d_in[3]; // fp32 bits [576000]
    // d_in[4] path_bias (redundant: bias=(1-sign)/2), d_in[5..6] scalars
    float* out = (float*)d_out;                                // fp32 [64][32000]

    // workspace: 9,409,536 B total (16B-aligned offsets)
    char* ws = (char*)d_ws;
    unsigned int*   pairs = (unsigned int*)ws;                   // 8,192,000 B
    unsigned short* idx2T = (unsigned short*)(ws + 8192000);     // 1,152,000 B
    ushort4*        attb  = (ushort4*)       (ws + 9344000);     //    65,536 B

    hipFuncSetAttribute(reinterpret_cast<const void*>(gather_pairs),
                        hipFuncAttributeMaxDynamicSharedMemorySize, ROWP * 4);

    prep<<<IDXB + 32, 256, 0, stream>>>(pidx, psign, idx2T, (const float4*)att, attb);
    gemm_logsig<<<500, 256, 0, stream>>>((const unsigned short*)attb, weight, pairs);
    gather_pairs<<<dim3(4, BS), 1024, ROWP * 4, stream>>>(pairs, idx2T, out);
}